// Round 13
// baseline (477.573 us; speedup 1.0000x reference)
//
#include <hip/hip_runtime.h>
#include <math.h>

#define N_NODES 100000
#define N_EDGES 1600000
#define HID 128
#define BN_EPS 1e-5f
#define BM 64
#define NTILES ((N_NODES + BM - 1) / BM)   // 1563
#define FUSED_BLOCKS 512
#define NSUB 4    // sublists per node; 16 nodes/wave * 4 = 64 chains = 1/lane
#define BN_BLOCKS 512

typedef __attribute__((ext_vector_type(8))) short bf16x8;
typedef __attribute__((ext_vector_type(4))) float f32x4;

__device__ inline unsigned short f2bf(float f) {
    unsigned u = __float_as_uint(f);
    unsigned r = u + 0x7FFFu + ((u >> 16) & 1u);   // RNE
    return (unsigned short)(r >> 16);
}
__device__ inline unsigned pk2(float lo, float hi) {
    return (unsigned)f2bf(lo) | ((unsigned)f2bf(hi) << 16);
}
__device__ inline float bflo(unsigned u) { return __uint_as_float(u << 16); }
__device__ inline float bfhi(unsigned u) { return __uint_as_float(u & 0xffff0000u); }

// Fused front: 2/3 of blocks do gate (bf16 cast + shadow zero + W prep),
// 1/3 do linked-list build (node-major head, NSUB=4). head preset by memset.
__global__ __launch_bounds__(256) void k_front(const float* __restrict__ x0,
                                               const float* __restrict__ x1,
                                               const float* __restrict__ mw,
                                               unsigned* __restrict__ gate_u2,
                                               float* __restrict__ shadow,
                                               const float* __restrict__ W1,
                                               const float* __restrict__ W2,
                                               unsigned short* __restrict__ W1T,
                                               unsigned short* __restrict__ W2T,
                                               const int* __restrict__ ei,
                                               int* __restrict__ head,
                                               int2* __restrict__ pair) {
    int bid = blockIdx.x, tid = threadIdx.x;
    int role = bid % 3;
    if (role < 2) {
        // gate block: gid in [0, 12500)
        int gid = (bid / 3) * 2 + role;
        int t = gid * 256 + tid;                       // 4-elem group index
        if (gid < 64) {
            shadow[t] = 0.0f;
            int k = t >> 7, n = t & 127;               // t < 16384
            W1T[n * HID + k] = f2bf(W1[t]);
            W2T[n * HID + k] = f2bf(W2[t]);
        }
        float s0 = 1.0f / (1.0f + expf(-mw[0]));
        float s1 = 1.0f / (1.0f + expf(-mw[1]));
        float4 a = ((const float4*)x0)[t];
        float4 b = ((const float4*)x1)[t];
        uint2 o;
        o.x = pk2(s0 * a.x + s1 * b.x, s0 * a.y + s1 * b.y);
        o.y = pk2(s0 * a.z + s1 * b.z, s0 * a.w + s1 * b.w);
        ((uint2*)gate_u2)[t] = o;
    } else {
        // build block: gid in [0, 6250)
        int e = (bid / 3) * 256 + tid;                 // exact: N_EDGES threads
        int src = ei[e];
        int dst = ei[N_EDGES + e];
        int old = atomicExch(&head[dst * NSUB + (e & (NSUB - 1))], e);
        pair[e] = make_int2(src, old);
    }
}

// Fused aggregate + MLP: persistent 512 blocks, weights in LDS once.
// Per 64-row tile: 4 waves x 16 nodes, one chain per lane (NSUB=4 sublists),
// register accumulation -> swizzled LDS -> GEMM1/ReLU/GEMM2 -> h2 bf16 + BN partials.
__global__ __launch_bounds__(256, 2) void k_fused(const unsigned* __restrict__ gu,
                                                  const int2* __restrict__ pair,
                                                  const int* __restrict__ head,
                                                  unsigned short* __restrict__ h2buf,
                                                  const unsigned short* __restrict__ W1T,
                                                  const unsigned short* __restrict__ W2T,
                                                  const float* __restrict__ b1,
                                                  const float* __restrict__ b2,
                                                  float* __restrict__ shadow) {
    __shared__ short lds_x[BM * HID];        // 16KB: X / X2 per tile, colsums at end
    __shared__ short lds_w1[HID * HID];      // 32KB
    __shared__ short lds_w2[HID * HID];      // 32KB

    const int tid = threadIdx.x;

    // stage weights once (bf16 W^T [n][k]) with XOR swizzle on 16B chunks
    for (int c = tid; c < 2048; c += 256) {
        int n = c >> 4, k16 = c & 15;
        int4 v1 = ((const int4*)W1T)[c];
        int4 v2 = ((const int4*)W2T)[c];
        int boff = n * 256 + ((k16 * 16) ^ ((n & 7) << 4));
        *(int4*)((char*)lds_w1 + boff) = v1;
        *(int4*)((char*)lds_w2 + boff) = v2;
    }

    const int wid = tid >> 6, lane = tid & 63;
    const int wrow = wid >> 1, wcol = wid & 1;
    const int l15 = lane & 15, l4 = lane >> 4;

    float b1g[4], b2g[4];
#pragma unroll
    for (int nf = 0; nf < 4; ++nf) {
        int n = wcol * 64 + nf * 16 + l15;
        b1g[nf] = b1[n];
        b2g[nf] = b2[n];
    }

    float psum[4] = {0.f, 0.f, 0.f, 0.f}, psq[4] = {0.f, 0.f, 0.f, 0.f};

    __syncthreads();   // weights ready

    for (int tile = blockIdx.x; tile < NTILES; tile += FUSED_BLOCKS) {
        const int m0 = tile * BM;

        // ---- aggregation phase (registers only) ----
        // lane owns chain (node m0 + wid*16 + (lane>>2), sublist lane&3)
        int mynode = m0 + wid * 16 + (lane >> 2);
        int e = (mynode < N_NODES) ? head[mynode * NSUB + (lane & 3)] : -1;

        float sx[16], sy[16];
#pragma unroll
        for (int j = 0; j < 16; ++j) {                 // self rows (wave-wide)
            int row = m0 + wid * 16 + j;
            unsigned g = (row < N_NODES) ? gu[(size_t)row * 64 + lane] : 0u;
            sx[j] = bflo(g); sy[j] = bfhi(g);
        }

        while (__any(e >= 0)) {
            int2 pv = make_int2(-1, -1);
            if (e >= 0) pv = pair[e];                  // dense per-lane clause
#pragma unroll
            for (int j = 0; j < 64; ++j) {
                int sv = __builtin_amdgcn_readlane(pv.x, j);   // SGPR broadcast
                if (sv >= 0) {
                    unsigned v = gu[(size_t)sv * 64 + lane];   // wave-wide 256B
                    sx[j >> 2] += bflo(v);
                    sy[j >> 2] += bfhi(v);
                }
            }
            e = pv.y;
        }

        // write aggregated rows -> swizzled LDS (row per j, conflict-free)
#pragma unroll
        for (int j = 0; j < 16; ++j) {
            int r = wid * 16 + j;
            int boff = r * 256 + ((lane * 4) ^ ((r & 7) << 4));
            *(unsigned*)((char*)lds_x + boff) = pk2(sx[j], sy[j]);
        }
        __syncthreads();

        // ---- GEMM1: Y = X @ W1 ----
        f32x4 acc1[2][4];
#pragma unroll
        for (int mf = 0; mf < 2; ++mf)
#pragma unroll
            for (int nf = 0; nf < 4; ++nf) acc1[mf][nf] = (f32x4){0.f, 0.f, 0.f, 0.f};

#pragma unroll
        for (int kc = 0; kc < 4; ++kc) {
            bf16x8 av[2], bv[4];
#pragma unroll
            for (int mf = 0; mf < 2; ++mf) {
                int r = wrow * 32 + mf * 16 + l15;
                int boff = r * 256 + (((kc * 64) + l4 * 16) ^ ((r & 7) << 4));
                av[mf] = *(const bf16x8*)((const char*)lds_x + boff);
            }
#pragma unroll
            for (int nf = 0; nf < 4; ++nf) {
                int n = wcol * 64 + nf * 16 + l15;
                int boff = n * 256 + (((kc * 64) + l4 * 16) ^ ((n & 7) << 4));
                bv[nf] = *(const bf16x8*)((const char*)lds_w1 + boff);
            }
#pragma unroll
            for (int mf = 0; mf < 2; ++mf)
#pragma unroll
                for (int nf = 0; nf < 4; ++nf)
                    acc1[mf][nf] = __builtin_amdgcn_mfma_f32_16x16x32_bf16(av[mf], bv[nf], acc1[mf][nf], 0, 0, 0);
        }

        __syncthreads();

        // bias1 + ReLU -> X2 (bf16, swizzled) into lds_x
#pragma unroll
        for (int mf = 0; mf < 2; ++mf)
#pragma unroll
            for (int nf = 0; nf < 4; ++nf) {
                int n = wcol * 64 + nf * 16 + l15;
#pragma unroll
                for (int r = 0; r < 4; ++r) {
                    int row = wrow * 32 + mf * 16 + l4 * 4 + r;
                    float v = fmaxf(acc1[mf][nf][r] + b1g[nf], 0.f);
                    int boff = row * 256 + ((2 * n) ^ ((row & 7) << 4));
                    *(unsigned short*)((char*)lds_x + boff) = f2bf(v);
                }
            }

        __syncthreads();

        // ---- GEMM2: h2 = X2 @ W2 ----
        f32x4 acc2[2][4];
#pragma unroll
        for (int mf = 0; mf < 2; ++mf)
#pragma unroll
            for (int nf = 0; nf < 4; ++nf) acc2[mf][nf] = (f32x4){0.f, 0.f, 0.f, 0.f};

#pragma unroll
        for (int kc = 0; kc < 4; ++kc) {
            bf16x8 av[2], bv[4];
#pragma unroll
            for (int mf = 0; mf < 2; ++mf) {
                int r = wrow * 32 + mf * 16 + l15;
                int boff = r * 256 + (((kc * 64) + l4 * 16) ^ ((r & 7) << 4));
                av[mf] = *(const bf16x8*)((const char*)lds_x + boff);
            }
#pragma unroll
            for (int nf = 0; nf < 4; ++nf) {
                int n = wcol * 64 + nf * 16 + l15;
                int boff = n * 256 + (((kc * 64) + l4 * 16) ^ ((n & 7) << 4));
                bv[nf] = *(const bf16x8*)((const char*)lds_w2 + boff);
            }
#pragma unroll
            for (int mf = 0; mf < 2; ++mf)
#pragma unroll
                for (int nf = 0; nf < 4; ++nf)
                    acc2[mf][nf] = __builtin_amdgcn_mfma_f32_16x16x32_bf16(av[mf], bv[nf], acc2[mf][nf], 0, 0, 0);
        }

        // epilogue: bias2, quantize h2 -> bf16, column partials in regs
#pragma unroll
        for (int mf = 0; mf < 2; ++mf)
#pragma unroll
            for (int nf = 0; nf < 4; ++nf) {
                int n = wcol * 64 + nf * 16 + l15;
#pragma unroll
                for (int r = 0; r < 4; ++r) {
                    int row = m0 + wrow * 32 + mf * 16 + l4 * 4 + r;
                    float v = acc2[mf][nf][r] + b2g[nf];
                    if (row < N_NODES) {
                        unsigned short q = f2bf(v);
                        float vq = __uint_as_float(((unsigned)q) << 16);
                        h2buf[(size_t)row * HID + n] = q;
                        psum[nf] += vq;
                        psq[nf] += vq * vq;
                    }
                }
            }

        __syncthreads();   // GEMM2 LDS reads done before next tile's X write
    }

    // final column-sum reduction: wave shuffle -> LDS -> one shadow add
    float* cs = (float*)lds_x;
    cs[tid] = 0.f;
    __syncthreads();
#pragma unroll
    for (int nf = 0; nf < 4; ++nf) {
        float s = psum[nf], q = psq[nf];
        s += __shfl_xor(s, 16); q += __shfl_xor(q, 16);
        s += __shfl_xor(s, 32); q += __shfl_xor(q, 32);
        if (lane < 16) {
            int n = wcol * 64 + nf * 16 + lane;
            atomicAdd(&cs[n], s);
            atomicAdd(&cs[HID + n], q);
        }
    }
    __syncthreads();
    atomicAdd(&shadow[(blockIdx.x & 63) * 256 + tid], cs[tid]);
}

// Fused finalize + BN apply: each block derives scale/shift from shadow (LDS),
// then grid-strides the bf16 h2 -> fp32 out stream.
__global__ __launch_bounds__(256) void k_bn2(const unsigned short* __restrict__ h2,
                                             const float* __restrict__ shadow,
                                             const float* __restrict__ gamma,
                                             const float* __restrict__ beta,
                                             float* __restrict__ out) {
    __shared__ float sc[256];                // scale[128], shift[128]
    int tid = threadIdx.x;
    if (tid < 128) {
        float sum = 0.f, sq = 0.f;
        for (int i = 0; i < 64; ++i) {
            sum += shadow[i * 256 + tid];
            sq  += shadow[i * 256 + 128 + tid];
        }
        float mean = sum * (1.0f / N_NODES);
        float var  = sq * (1.0f / N_NODES) - mean * mean;
        float r = rsqrtf(var + BN_EPS);
        float scale = gamma[tid] * r;
        sc[tid]       = scale;
        sc[128 + tid] = beta[tid] - mean * scale;
    }
    __syncthreads();
    int c4 = tid & 31;
    float4 scale = ((const float4*)sc)[c4];
    float4 shift = ((const float4*)sc)[32 + c4];
    const int total = N_NODES * HID / 4;               // 3,200,000 uint2 groups
    for (int t = blockIdx.x * 256 + tid; t < total; t += BN_BLOCKS * 256) {
        uint2 hv = ((const uint2*)h2)[t];
        float4 o;
        o.x = bflo(hv.x) * scale.x + shift.x;
        o.y = bfhi(hv.x) * scale.y + shift.y;
        o.z = bflo(hv.y) * scale.z + shift.z;
        o.w = bfhi(hv.y) * scale.w + shift.w;
        ((float4*)out)[t] = o;
    }
}

extern "C" void kernel_launch(void* const* d_in, const int* in_sizes, int n_in,
                              void* d_out, int out_size, void* d_ws, size_t ws_size,
                              hipStream_t stream) {
    const float* x0 = (const float*)d_in[0];
    const float* x1 = (const float*)d_in[1];
    const int*   ei = (const int*)d_in[2];
    const float* mw = (const float*)d_in[3];
    const float* W1 = (const float*)d_in[4];
    const float* b1 = (const float*)d_in[5];
    const float* W2 = (const float*)d_in[6];
    const float* b2 = (const float*)d_in[7];
    const float* gamma = (const float*)d_in[8];
    const float* beta  = (const float*)d_in[9];

    float* out = (float*)d_out;                            // gate(bf16) scratch -> final fp32

    unsigned short* hbuf = (unsigned short*)d_ws;          // 12.8M bf16 (h2)
    float* shadow = (float*)(hbuf + (size_t)N_NODES * HID);// 16384
    unsigned short* W1T = (unsigned short*)(shadow + 16384); // 16384 u16
    unsigned short* W2T = W1T + 16384;                     // 16384 u16
    int* head    = (int*)(W2T + 16384);                    // 100,000 * 4, node-major
    int2* pair   = (int2*)(head + NSUB * N_NODES);         // 1,600,000 int2 (8B aligned)

    // head = -1 (0xFF bytes); async memset is graph-capture safe
    hipMemsetAsync(head, 0xFF, (size_t)NSUB * N_NODES * sizeof(int), stream);

    // fused gate + build: 12500 gate blocks + 6250 build blocks, interleaved 2:1
    k_front<<<18750, 256, 0, stream>>>(x0, x1, mw, (unsigned*)out, shadow,
                                       W1, W2, W1T, W2T, ei, head, pair);
    // fused aggregate + MLP (persistent)
    k_fused<<<FUSED_BLOCKS, 256, 0, stream>>>((const unsigned*)out, pair, head, hbuf,
                                              W1T, W2T, b1, b2, shadow);
    // finalize + BN apply
    k_bn2<<<BN_BLOCKS, 256, 0, stream>>>(hbuf, shadow, gamma, beta, out);
}

// Round 14
// 238.949 us; speedup vs baseline: 1.9986x; 1.9986x over previous
//
#include <hip/hip_runtime.h>
#include <math.h>

#define N_NODES 100000
#define N_EDGES 1600000
#define HID 128
#define BN_EPS 1e-5f
#define BM 64
#define NTILES ((N_NODES + BM - 1) / BM)   // 1563
#define MLP_BLOCKS 512
#define NSUB 16   // sublists per node -> avg chain length 1
#define NPW 4     // nodes per wave (NPW*NSUB = 64 chains, one per lane)
#define BN_BLOCKS 512

typedef __attribute__((ext_vector_type(8))) short bf16x8;
typedef __attribute__((ext_vector_type(4))) float f32x4;

__device__ inline unsigned short f2bf(float f) {
    unsigned u = __float_as_uint(f);
    unsigned r = u + 0x7FFFu + ((u >> 16) & 1u);   // RNE
    return (unsigned short)(r >> 16);
}
__device__ inline unsigned pk2(float lo, float hi) {
    return (unsigned)f2bf(lo) | ((unsigned)f2bf(hi) << 16);
}
__device__ inline float bflo(unsigned u) { return __uint_as_float(u << 16); }
__device__ inline float bfhi(unsigned u) { return __uint_as_float(u & 0xffff0000u); }

// Fused front: 2/3 of blocks do gate (bf16 cast + shadow zero + W prep),
// 1/3 do linked-list build. Independent work; head pre-initialized by memset.
__global__ __launch_bounds__(256) void k_front(const float* __restrict__ x0,
                                               const float* __restrict__ x1,
                                               const float* __restrict__ mw,
                                               unsigned* __restrict__ gate_u2,
                                               float* __restrict__ shadow,
                                               const float* __restrict__ W1,
                                               const float* __restrict__ W2,
                                               unsigned short* __restrict__ W1T,
                                               unsigned short* __restrict__ W2T,
                                               const int* __restrict__ ei,
                                               int* __restrict__ head,
                                               int2* __restrict__ pair) {
    int bid = blockIdx.x, tid = threadIdx.x;
    int role = bid % 3;
    if (role < 2) {
        // gate block: gid in [0, 12500)
        int gid = (bid / 3) * 2 + role;
        int t = gid * 256 + tid;                       // 4-elem group index
        if (gid < 64) {
            shadow[t] = 0.0f;
            int k = t >> 7, n = t & 127;               // t < 16384
            W1T[n * HID + k] = f2bf(W1[t]);
            W2T[n * HID + k] = f2bf(W2[t]);
        }
        float s0 = 1.0f / (1.0f + expf(-mw[0]));
        float s1 = 1.0f / (1.0f + expf(-mw[1]));
        float4 a = ((const float4*)x0)[t];
        float4 b = ((const float4*)x1)[t];
        uint2 o;
        o.x = pk2(s0 * a.x + s1 * b.x, s0 * a.y + s1 * b.y);
        o.y = pk2(s0 * a.z + s1 * b.z, s0 * a.w + s1 * b.w);
        ((uint2*)gate_u2)[t] = o;
    } else {
        // build block: gid in [0, 6250)
        int e = (bid / 3) * 256 + tid;                 // exact: N_EDGES threads
        int src = ei[e];
        int dst = ei[N_EDGES + e];
        int old = atomicExch(&head[dst * NSUB + (e & (NSUB - 1))], e);
        pair[e] = make_int2(src, old);
    }
}

// gather-sum: 64 chains per wave (one per lane), wave-wide dense row gathers.
// head is node-major: per-wave chain-head read is one contiguous 256B block.
__global__ __launch_bounds__(256) void k_agg(const unsigned* __restrict__ gu,
                                             const int2* __restrict__ pair,
                                             const int* __restrict__ head,
                                             unsigned* __restrict__ hbuf_u) {
    int wid = threadIdx.x >> 6, lane = threadIdx.x & 63;
    int nbase = (blockIdx.x * 4 + wid) * NPW;          // exact: 6250 blocks
    // lane l owns chain (node nbase + (l>>4), sublist l&15)
    int e = head[(nbase + (lane >> 4)) * NSUB + (lane & 15)];

    float sx[NPW], sy[NPW];
#pragma unroll
    for (int j = 0; j < NPW; ++j) {
        unsigned g = gu[(size_t)(nbase + j) * 64 + lane];   // self row
        sx[j] = bflo(g); sy[j] = bfhi(g);
    }

    while (__any(e >= 0)) {
        int2 pv = make_int2(-1, -1);
        if (e >= 0) pv = pair[e];                      // one dense per-lane clause
#pragma unroll
        for (int j = 0; j < 64; ++j) {
            int sv = __builtin_amdgcn_readlane(pv.x, j);   // SGPR; scalar skip
            if (sv >= 0) {
                unsigned v = gu[(size_t)sv * 64 + lane];   // wave-wide 256B gather
                sx[j >> 4] += bflo(v);
                sy[j >> 4] += bfhi(v);
            }
        }
        e = pv.y;
    }
#pragma unroll
    for (int j = 0; j < NPW; ++j)
        hbuf_u[(size_t)(nbase + j) * 64 + lane] = pk2(sx[j], sy[j]);
}

// Persistent MFMA MLP: 512 blocks, weights staged ONCE.
// GEMM1 A-fragments loaded DIRECTLY from global h (bf16) — no X staging, 2 barriers/tile.
// writes h2 (bf16) IN PLACE; column sums in regs -> shadow at end.
__global__ __launch_bounds__(256, 2) void k_mlp(unsigned short* __restrict__ hbuf,
                                                const unsigned short* __restrict__ W1T,
                                                const unsigned short* __restrict__ W2T,
                                                const float* __restrict__ b1,
                                                const float* __restrict__ b2,
                                                float* __restrict__ shadow) {
    __shared__ short lds_x[BM * HID];        // 16KB: X2 per tile, colsums at end
    __shared__ short lds_w1[HID * HID];      // 32KB
    __shared__ short lds_w2[HID * HID];      // 32KB

    const int tid = threadIdx.x;

    // stage weights once (bf16 W^T [n][k]) with XOR swizzle on 16B chunks
    for (int c = tid; c < 2048; c += 256) {
        int n = c >> 4, k16 = c & 15;
        int4 v1 = ((const int4*)W1T)[c];
        int4 v2 = ((const int4*)W2T)[c];
        int boff = n * 256 + ((k16 * 16) ^ ((n & 7) << 4));
        *(int4*)((char*)lds_w1 + boff) = v1;
        *(int4*)((char*)lds_w2 + boff) = v2;
    }

    const int wid = tid >> 6, lane = tid & 63;
    const int wrow = wid >> 1, wcol = wid & 1;
    const int l15 = lane & 15, l4 = lane >> 4;

    float b1g[4], b2g[4];
#pragma unroll
    for (int nf = 0; nf < 4; ++nf) {
        int n = wcol * 64 + nf * 16 + l15;
        b1g[nf] = b1[n];
        b2g[nf] = b2[n];
    }

    float psum[4] = {0.f, 0.f, 0.f, 0.f}, psq[4] = {0.f, 0.f, 0.f, 0.f};

    __syncthreads();   // weights ready

    for (int tile = blockIdx.x; tile < NTILES; tile += MLP_BLOCKS) {
        const int m0 = tile * BM;

        // GEMM1 A-fragments direct from global: lane reads 16B at
        // (m0 + wrow*32 + mf*16 + l15) * HID + kc*32 + l4*8   (bf16 elems)
        bf16x8 avg[2][4];
#pragma unroll
        for (int mf = 0; mf < 2; ++mf) {
            int row = m0 + wrow * 32 + mf * 16 + l15;
#pragma unroll
            for (int kc = 0; kc < 4; ++kc) {
                bf16x8 z = {0, 0, 0, 0, 0, 0, 0, 0};
                if (row < N_NODES)
                    z = *(const bf16x8*)(hbuf + (size_t)row * HID + kc * 32 + l4 * 8);
                avg[mf][kc] = z;
            }
        }

        // GEMM1: Y = X @ W1 (A from registers, B from LDS)
        f32x4 acc1[2][4];
#pragma unroll
        for (int mf = 0; mf < 2; ++mf)
#pragma unroll
            for (int nf = 0; nf < 4; ++nf) acc1[mf][nf] = (f32x4){0.f, 0.f, 0.f, 0.f};

#pragma unroll
        for (int kc = 0; kc < 4; ++kc) {
            bf16x8 bv[4];
#pragma unroll
            for (int nf = 0; nf < 4; ++nf) {
                int n = wcol * 64 + nf * 16 + l15;
                int boff = n * 256 + (((kc * 64) + l4 * 16) ^ ((n & 7) << 4));
                bv[nf] = *(const bf16x8*)((const char*)lds_w1 + boff);
            }
#pragma unroll
            for (int mf = 0; mf < 2; ++mf)
#pragma unroll
                for (int nf = 0; nf < 4; ++nf)
                    acc1[mf][nf] = __builtin_amdgcn_mfma_f32_16x16x32_bf16(avg[mf][kc], bv[nf], acc1[mf][nf], 0, 0, 0);
        }

        // bias1 + ReLU -> X2 (bf16, swizzled) into lds_x
        // (lds_x is free here: previous tile's GEMM2 reads finished before its end-of-tile sync)
#pragma unroll
        for (int mf = 0; mf < 2; ++mf)
#pragma unroll
            for (int nf = 0; nf < 4; ++nf) {
                int n = wcol * 64 + nf * 16 + l15;
#pragma unroll
                for (int r = 0; r < 4; ++r) {
                    int row = wrow * 32 + mf * 16 + l4 * 4 + r;
                    float v = fmaxf(acc1[mf][nf][r] + b1g[nf], 0.f);
                    int boff = row * 256 + ((2 * n) ^ ((row & 7) << 4));
                    *(unsigned short*)((char*)lds_x + boff) = f2bf(v);
                }
            }

        __syncthreads();   // X2 visible to all waves

        // GEMM2: h2 = X2 @ W2
        f32x4 acc2[2][4];
#pragma unroll
        for (int mf = 0; mf < 2; ++mf)
#pragma unroll
            for (int nf = 0; nf < 4; ++nf) acc2[mf][nf] = (f32x4){0.f, 0.f, 0.f, 0.f};

#pragma unroll
        for (int kc = 0; kc < 4; ++kc) {
            bf16x8 av[2], bv[4];
#pragma unroll
            for (int mf = 0; mf < 2; ++mf) {
                int r = wrow * 32 + mf * 16 + l15;
                int boff = r * 256 + (((kc * 64) + l4 * 16) ^ ((r & 7) << 4));
                av[mf] = *(const bf16x8*)((const char*)lds_x + boff);
            }
#pragma unroll
            for (int nf = 0; nf < 4; ++nf) {
                int n = wcol * 64 + nf * 16 + l15;
                int boff = n * 256 + (((kc * 64) + l4 * 16) ^ ((n & 7) << 4));
                bv[nf] = *(const bf16x8*)((const char*)lds_w2 + boff);
            }
#pragma unroll
            for (int mf = 0; mf < 2; ++mf)
#pragma unroll
                for (int nf = 0; nf < 4; ++nf)
                    acc2[mf][nf] = __builtin_amdgcn_mfma_f32_16x16x32_bf16(av[mf], bv[nf], acc2[mf][nf], 0, 0, 0);
        }

        // epilogue: bias2, quantize h2 -> bf16 in place, column partials in regs
#pragma unroll
        for (int mf = 0; mf < 2; ++mf)
#pragma unroll
            for (int nf = 0; nf < 4; ++nf) {
                int n = wcol * 64 + nf * 16 + l15;
#pragma unroll
                for (int r = 0; r < 4; ++r) {
                    int row = m0 + wrow * 32 + mf * 16 + l4 * 4 + r;
                    float v = acc2[mf][nf][r] + b2g[nf];
                    if (row < N_NODES) {
                        unsigned short q = f2bf(v);
                        float vq = __uint_as_float(((unsigned)q) << 16);
                        hbuf[(size_t)row * HID + n] = q;
                        psum[nf] += vq;
                        psq[nf] += vq * vq;
                    }
                }
            }

        __syncthreads();   // GEMM2 LDS reads done before next tile's X2 write
    }

    // final column-sum reduction: wave shuffle -> LDS -> one shadow add
    float* cs = (float*)lds_x;
    cs[tid] = 0.f;
    __syncthreads();
#pragma unroll
    for (int nf = 0; nf < 4; ++nf) {
        float s = psum[nf], q = psq[nf];
        s += __shfl_xor(s, 16); q += __shfl_xor(q, 16);
        s += __shfl_xor(s, 32); q += __shfl_xor(q, 32);
        if (lane < 16) {
            int n = wcol * 64 + nf * 16 + lane;
            atomicAdd(&cs[n], s);
            atomicAdd(&cs[HID + n], q);
        }
    }
    __syncthreads();
    atomicAdd(&shadow[(blockIdx.x & 63) * 256 + tid], cs[tid]);
}

// Fused finalize + BN apply: each block derives scale/shift from shadow (LDS),
// then grid-strides the bf16 h2 -> fp32 out stream.
__global__ __launch_bounds__(256) void k_bn2(const unsigned short* __restrict__ h2,
                                             const float* __restrict__ shadow,
                                             const float* __restrict__ gamma,
                                             const float* __restrict__ beta,
                                             float* __restrict__ out) {
    __shared__ float sc[256];                // scale[128], shift[128]
    int tid = threadIdx.x;
    if (tid < 128) {
        float sum = 0.f, sq = 0.f;
        for (int i = 0; i < 64; ++i) {
            sum += shadow[i * 256 + tid];
            sq  += shadow[i * 256 + 128 + tid];
        }
        float mean = sum * (1.0f / N_NODES);
        float var  = sq * (1.0f / N_NODES) - mean * mean;
        float r = rsqrtf(var + BN_EPS);
        float scale = gamma[tid] * r;
        sc[tid]       = scale;
        sc[128 + tid] = beta[tid] - mean * scale;
    }
    __syncthreads();
    int c4 = tid & 31;
    float4 scale = ((const float4*)sc)[c4];
    float4 shift = ((const float4*)sc)[32 + c4];
    const int total = N_NODES * HID / 4;               // 3,200,000 uint2 groups
    for (int t = blockIdx.x * 256 + tid; t < total; t += BN_BLOCKS * 256) {
        uint2 hv = ((const uint2*)h2)[t];
        float4 o;
        o.x = bflo(hv.x) * scale.x + shift.x;
        o.y = bfhi(hv.x) * scale.y + shift.y;
        o.z = bflo(hv.y) * scale.z + shift.z;
        o.w = bfhi(hv.y) * scale.w + shift.w;
        ((float4*)out)[t] = o;
    }
}

extern "C" void kernel_launch(void* const* d_in, const int* in_sizes, int n_in,
                              void* d_out, int out_size, void* d_ws, size_t ws_size,
                              hipStream_t stream) {
    const float* x0 = (const float*)d_in[0];
    const float* x1 = (const float*)d_in[1];
    const int*   ei = (const int*)d_in[2];
    const float* mw = (const float*)d_in[3];
    const float* W1 = (const float*)d_in[4];
    const float* b1 = (const float*)d_in[5];
    const float* W2 = (const float*)d_in[6];
    const float* b2 = (const float*)d_in[7];
    const float* gamma = (const float*)d_in[8];
    const float* beta  = (const float*)d_in[9];

    float* out = (float*)d_out;                            // gate(bf16) scratch -> final fp32

    unsigned short* hbuf = (unsigned short*)d_ws;          // 12.8M bf16 (h, then h2)
    float* shadow = (float*)(hbuf + (size_t)N_NODES * HID);// 16384
    float* sc     = shadow + 16384;                        // 256 (layout keep)
    unsigned short* W1T = (unsigned short*)(sc + 256);     // 16384 u16
    unsigned short* W2T = W1T + 16384;                     // 16384 u16
    int* head    = (int*)(W2T + 16384);                    // 100,000 * 16, node-major
    int2* pair   = (int2*)(head + NSUB * N_NODES);         // 1,600,000 int2 (8B aligned)

    // head = -1 (0xFF bytes); async memset is graph-capture safe
    hipMemsetAsync(head, 0xFF, (size_t)NSUB * N_NODES * sizeof(int), stream);

    // fused gate + build: 12500 gate blocks + 6250 build blocks, interleaved 2:1
    k_front<<<18750, 256, 0, stream>>>(x0, x1, mw, (unsigned*)out, shadow,
                                       W1, W2, W1T, W2T, ei, head, pair);
    k_agg<<<N_NODES / (4 * NPW), 256, 0, stream>>>((const unsigned*)out, pair, head,
                                                   (unsigned*)hbuf);
    k_mlp<<<MLP_BLOCKS, 256, 0, stream>>>(hbuf, W1T, W2T, b1, b2, shadow);
    k_bn2<<<BN_BLOCKS, 256, 0, stream>>>(hbuf, shadow, gamma, beta, out);
}

// Round 16
// 238.155 us; speedup vs baseline: 2.0053x; 1.0033x over previous
//
#include <hip/hip_runtime.h>
#include <math.h>

#define N_NODES 100000
#define N_EDGES 1600000
#define HID 128
#define BN_EPS 1e-5f
#define BM 64
#define NTILES ((N_NODES + BM - 1) / BM)   // 1563
#define MLP_BLOCKS 512
#define NSUB 16   // sublists per node -> avg chain length 1
#define NPW 4     // nodes per wave (NPW*NSUB = 64 chains, one per lane)
#define BN_BLOCKS 512

typedef __attribute__((ext_vector_type(8))) short bf16x8;
typedef __attribute__((ext_vector_type(4))) float f32x4;

__device__ inline unsigned short f2bf(float f) {
    unsigned u = __float_as_uint(f);
    unsigned r = u + 0x7FFFu + ((u >> 16) & 1u);   // RNE
    return (unsigned short)(r >> 16);
}
__device__ inline unsigned pk2(float lo, float hi) {
    return (unsigned)f2bf(lo) | ((unsigned)f2bf(hi) << 16);
}
__device__ inline float bflo(unsigned u) { return __uint_as_float(u << 16); }
__device__ inline float bfhi(unsigned u) { return __uint_as_float(u & 0xffff0000u); }

// Fused front: 2/3 of blocks do gate (bf16 cast + shadow zero + W prep),
// 1/3 do linked-list build. Independent work; head pre-initialized by memset.
__global__ __launch_bounds__(256) void k_front(const float* __restrict__ x0,
                                               const float* __restrict__ x1,
                                               const float* __restrict__ mw,
                                               unsigned* __restrict__ gate_u2,
                                               float* __restrict__ shadow,
                                               const float* __restrict__ W1,
                                               const float* __restrict__ W2,
                                               unsigned short* __restrict__ W1T,
                                               unsigned short* __restrict__ W2T,
                                               const int* __restrict__ ei,
                                               int* __restrict__ head,
                                               int2* __restrict__ pair) {
    int bid = blockIdx.x, tid = threadIdx.x;
    int role = bid % 3;
    if (role < 2) {
        // gate block: gid in [0, 12500)
        int gid = (bid / 3) * 2 + role;
        int t = gid * 256 + tid;                       // 4-elem group index
        if (gid < 64) {
            shadow[t] = 0.0f;
            int k = t >> 7, n = t & 127;               // t < 16384
            W1T[n * HID + k] = f2bf(W1[t]);
            W2T[n * HID + k] = f2bf(W2[t]);
        }
        float s0 = 1.0f / (1.0f + expf(-mw[0]));
        float s1 = 1.0f / (1.0f + expf(-mw[1]));
        float4 a = ((const float4*)x0)[t];
        float4 b = ((const float4*)x1)[t];
        uint2 o;
        o.x = pk2(s0 * a.x + s1 * b.x, s0 * a.y + s1 * b.y);
        o.y = pk2(s0 * a.z + s1 * b.z, s0 * a.w + s1 * b.w);
        ((uint2*)gate_u2)[t] = o;
    } else {
        // build block: gid in [0, 6250)
        int e = (bid / 3) * 256 + tid;                 // exact: N_EDGES threads
        int src = ei[e];
        int dst = ei[N_EDGES + e];
        int old = atomicExch(&head[dst * NSUB + (e & (NSUB - 1))], e);
        pair[e] = make_int2(src, old);
    }
}

// gather-sum: 64 chains per wave (one per lane), wave-wide dense row gathers.
// head is node-major: per-wave chain-head read is one contiguous 256B block.
__global__ __launch_bounds__(256) void k_agg(const unsigned* __restrict__ gu,
                                             const int2* __restrict__ pair,
                                             const int* __restrict__ head,
                                             unsigned* __restrict__ hbuf_u) {
    int wid = threadIdx.x >> 6, lane = threadIdx.x & 63;
    int nbase = (blockIdx.x * 4 + wid) * NPW;          // exact: 6250 blocks
    // lane l owns chain (node nbase + (l>>4), sublist l&15)
    int e = head[(nbase + (lane >> 4)) * NSUB + (lane & 15)];

    float sx[NPW], sy[NPW];
#pragma unroll
    for (int j = 0; j < NPW; ++j) {
        unsigned g = gu[(size_t)(nbase + j) * 64 + lane];   // self row
        sx[j] = bflo(g); sy[j] = bfhi(g);
    }

    while (__any(e >= 0)) {
        int2 pv = make_int2(-1, -1);
        if (e >= 0) pv = pair[e];                      // one dense per-lane clause
#pragma unroll
        for (int j = 0; j < 64; ++j) {
            int sv = __builtin_amdgcn_readlane(pv.x, j);   // SGPR; scalar skip
            if (sv >= 0) {
                unsigned v = gu[(size_t)sv * 64 + lane];   // wave-wide 256B gather
                sx[j >> 4] += bflo(v);
                sy[j >> 4] += bfhi(v);
            }
        }
        e = pv.y;
    }
#pragma unroll
    for (int j = 0; j < NPW; ++j)
        hbuf_u[(size_t)(nbase + j) * 64 + lane] = pk2(sx[j], sy[j]);
}

// Persistent MFMA MLP: 512 blocks, weights staged ONCE, register-prefetched X.
// reads h (bf16), writes h2 (bf16) IN PLACE; column sums in regs -> shadow at end.
__global__ __launch_bounds__(256, 2) void k_mlp(unsigned short* __restrict__ hbuf,
                                                const unsigned short* __restrict__ W1T,
                                                const unsigned short* __restrict__ W2T,
                                                const float* __restrict__ b1,
                                                const float* __restrict__ b2,
                                                float* __restrict__ shadow) {
    __shared__ short lds_x[BM * HID];        // 16KB: X / X2 per tile, colsums at end
    __shared__ short lds_w1[HID * HID];      // 32KB
    __shared__ short lds_w2[HID * HID];      // 32KB

    const int tid = threadIdx.x;

    // stage weights once (bf16 W^T [n][k]) with XOR swizzle on 16B chunks
    for (int c = tid; c < 2048; c += 256) {
        int n = c >> 4, k16 = c & 15;
        int4 v1 = ((const int4*)W1T)[c];
        int4 v2 = ((const int4*)W2T)[c];
        int boff = n * 256 + ((k16 * 16) ^ ((n & 7) << 4));
        *(int4*)((char*)lds_w1 + boff) = v1;
        *(int4*)((char*)lds_w2 + boff) = v2;
    }

    const int wid = tid >> 6, lane = tid & 63;
    const int wrow = wid >> 1, wcol = wid & 1;
    const int l15 = lane & 15, l4 = lane >> 4;

    float b1g[4], b2g[4];
#pragma unroll
    for (int nf = 0; nf < 4; ++nf) {
        int n = wcol * 64 + nf * 16 + l15;
        b1g[nf] = b1[n];
        b2g[nf] = b2[n];
    }

    float psum[4] = {0.f, 0.f, 0.f, 0.f}, psq[4] = {0.f, 0.f, 0.f, 0.f};

    // prefetch first tile's X into registers (4 x int4 per thread)
    int4 xr[4];
    int tile0 = blockIdx.x;
#pragma unroll
    for (int i = 0; i < 4; ++i) {
        int c = tid + i * 256;                         // c in [0, 1024)
        int row = tile0 * BM + (c >> 4);
        xr[i] = make_int4(0, 0, 0, 0);
        if (tile0 < NTILES && row < N_NODES)
            xr[i] = ((const int4*)(hbuf + (size_t)row * HID))[c & 15];
    }

    __syncthreads();   // weights ready

    for (int tile = blockIdx.x; tile < NTILES; tile += MLP_BLOCKS) {
        const int m0 = tile * BM;

        // write prefetched X regs -> swizzled LDS
#pragma unroll
        for (int i = 0; i < 4; ++i) {
            int c = tid + i * 256;
            int r = c >> 4, k16 = c & 15;
            int boff = r * 256 + ((k16 * 16) ^ ((r & 7) << 4));
            *(int4*)((char*)lds_x + boff) = xr[i];
        }
        __syncthreads();

        // GEMM1: Y = X @ W1
        f32x4 acc1[2][4];
#pragma unroll
        for (int mf = 0; mf < 2; ++mf)
#pragma unroll
            for (int nf = 0; nf < 4; ++nf) acc1[mf][nf] = (f32x4){0.f, 0.f, 0.f, 0.f};

#pragma unroll
        for (int kc = 0; kc < 4; ++kc) {
            bf16x8 av[2], bv[4];
#pragma unroll
            for (int mf = 0; mf < 2; ++mf) {
                int r = wrow * 32 + mf * 16 + l15;
                int boff = r * 256 + (((kc * 64) + l4 * 16) ^ ((r & 7) << 4));
                av[mf] = *(const bf16x8*)((const char*)lds_x + boff);
            }
#pragma unroll
            for (int nf = 0; nf < 4; ++nf) {
                int n = wcol * 64 + nf * 16 + l15;
                int boff = n * 256 + (((kc * 64) + l4 * 16) ^ ((n & 7) << 4));
                bv[nf] = *(const bf16x8*)((const char*)lds_w1 + boff);
            }
#pragma unroll
            for (int mf = 0; mf < 2; ++mf)
#pragma unroll
                for (int nf = 0; nf < 4; ++nf)
                    acc1[mf][nf] = __builtin_amdgcn_mfma_f32_16x16x32_bf16(av[mf], bv[nf], acc1[mf][nf], 0, 0, 0);
        }

        __syncthreads();

        // bias1 + ReLU -> X2 (bf16, swizzled) into lds_x
#pragma unroll
        for (int mf = 0; mf < 2; ++mf)
#pragma unroll
            for (int nf = 0; nf < 4; ++nf) {
                int n = wcol * 64 + nf * 16 + l15;
#pragma unroll
                for (int r = 0; r < 4; ++r) {
                    int row = wrow * 32 + mf * 16 + l4 * 4 + r;
                    float v = fmaxf(acc1[mf][nf][r] + b1g[nf], 0.f);
                    int boff = row * 256 + ((2 * n) ^ ((row & 7) << 4));
                    *(unsigned short*)((char*)lds_x + boff) = f2bf(v);
                }
            }

        __syncthreads();

        // issue NEXT tile's X prefetch (overlaps GEMM2 + epilogue)
        int tnext = tile + MLP_BLOCKS;
#pragma unroll
        for (int i = 0; i < 4; ++i) {
            int c = tid + i * 256;
            int row = tnext * BM + (c >> 4);
            int4 v = make_int4(0, 0, 0, 0);
            if (tnext < NTILES && row < N_NODES)
                v = ((const int4*)(hbuf + (size_t)row * HID))[c & 15];
            xr[i] = v;
        }

        // GEMM2: h2 = X2 @ W2
        f32x4 acc2[2][4];
#pragma unroll
        for (int mf = 0; mf < 2; ++mf)
#pragma unroll
            for (int nf = 0; nf < 4; ++nf) acc2[mf][nf] = (f32x4){0.f, 0.f, 0.f, 0.f};

#pragma unroll
        for (int kc = 0; kc < 4; ++kc) {
            bf16x8 av[2], bv[4];
#pragma unroll
            for (int mf = 0; mf < 2; ++mf) {
                int r = wrow * 32 + mf * 16 + l15;
                int boff = r * 256 + (((kc * 64) + l4 * 16) ^ ((r & 7) << 4));
                av[mf] = *(const bf16x8*)((const char*)lds_x + boff);
            }
#pragma unroll
            for (int nf = 0; nf < 4; ++nf) {
                int n = wcol * 64 + nf * 16 + l15;
                int boff = n * 256 + (((kc * 64) + l4 * 16) ^ ((n & 7) << 4));
                bv[nf] = *(const bf16x8*)((const char*)lds_w2 + boff);
            }
#pragma unroll
            for (int mf = 0; mf < 2; ++mf)
#pragma unroll
                for (int nf = 0; nf < 4; ++nf)
                    acc2[mf][nf] = __builtin_amdgcn_mfma_f32_16x16x32_bf16(av[mf], bv[nf], acc2[mf][nf], 0, 0, 0);
        }

        // epilogue: bias2, quantize h2 -> bf16 in place, column partials in regs
#pragma unroll
        for (int mf = 0; mf < 2; ++mf)
#pragma unroll
            for (int nf = 0; nf < 4; ++nf) {
                int n = wcol * 64 + nf * 16 + l15;
#pragma unroll
                for (int r = 0; r < 4; ++r) {
                    int row = m0 + wrow * 32 + mf * 16 + l4 * 4 + r;
                    float v = acc2[mf][nf][r] + b2g[nf];
                    if (row < N_NODES) {
                        unsigned short q = f2bf(v);
                        float vq = __uint_as_float(((unsigned)q) << 16);
                        hbuf[(size_t)row * HID + n] = q;
                        psum[nf] += vq;
                        psq[nf] += vq * vq;
                    }
                }
            }

        __syncthreads();   // all GEMM2 LDS reads done before next tile's X write
    }

    // final column-sum reduction: wave shuffle -> LDS -> one shadow add
    float* cs = (float*)lds_x;
    cs[tid] = 0.f;
    __syncthreads();
#pragma unroll
    for (int nf = 0; nf < 4; ++nf) {
        float s = psum[nf], q = psq[nf];
        s += __shfl_xor(s, 16); q += __shfl_xor(q, 16);
        s += __shfl_xor(s, 32); q += __shfl_xor(q, 32);
        if (lane < 16) {
            int n = wcol * 64 + nf * 16 + lane;
            atomicAdd(&cs[n], s);
            atomicAdd(&cs[HID + n], q);
        }
    }
    __syncthreads();
    atomicAdd(&shadow[(blockIdx.x & 63) * 256 + tid], cs[tid]);
}

// Fused finalize + BN apply: each block derives scale/shift from shadow (LDS),
// then grid-strides the bf16 h2 -> fp32 out stream.
__global__ __launch_bounds__(256) void k_bn2(const unsigned short* __restrict__ h2,
                                             const float* __restrict__ shadow,
                                             const float* __restrict__ gamma,
                                             const float* __restrict__ beta,
                                             float* __restrict__ out) {
    __shared__ float sc[256];                // scale[128], shift[128]
    int tid = threadIdx.x;
    if (tid < 128) {
        float sum = 0.f, sq = 0.f;
        for (int i = 0; i < 64; ++i) {
            sum += shadow[i * 256 + tid];
            sq  += shadow[i * 256 + 128 + tid];
        }
        float mean = sum * (1.0f / N_NODES);
        float var  = sq * (1.0f / N_NODES) - mean * mean;
        float r = rsqrtf(var + BN_EPS);
        float scale = gamma[tid] * r;
        sc[tid]       = scale;
        sc[128 + tid] = beta[tid] - mean * scale;
    }
    __syncthreads();
    int c4 = tid & 31;
    float4 scale = ((const float4*)sc)[c4];
    float4 shift = ((const float4*)sc)[32 + c4];
    const int total = N_NODES * HID / 4;               // 3,200,000 uint2 groups
    for (int t = blockIdx.x * 256 + tid; t < total; t += BN_BLOCKS * 256) {
        uint2 hv = ((const uint2*)h2)[t];
        float4 o;
        o.x = bflo(hv.x) * scale.x + shift.x;
        o.y = bfhi(hv.x) * scale.y + shift.y;
        o.z = bflo(hv.y) * scale.z + shift.z;
        o.w = bfhi(hv.y) * scale.w + shift.w;
        ((float4*)out)[t] = o;
    }
}

extern "C" void kernel_launch(void* const* d_in, const int* in_sizes, int n_in,
                              void* d_out, int out_size, void* d_ws, size_t ws_size,
                              hipStream_t stream) {
    const float* x0 = (const float*)d_in[0];
    const float* x1 = (const float*)d_in[1];
    const int*   ei = (const int*)d_in[2];
    const float* mw = (const float*)d_in[3];
    const float* W1 = (const float*)d_in[4];
    const float* b1 = (const float*)d_in[5];
    const float* W2 = (const float*)d_in[6];
    const float* b2 = (const float*)d_in[7];
    const float* gamma = (const float*)d_in[8];
    const float* beta  = (const float*)d_in[9];

    float* out = (float*)d_out;                            // gate(bf16) scratch -> final fp32

    unsigned short* hbuf = (unsigned short*)d_ws;          // 12.8M bf16 (h, then h2)
    float* shadow = (float*)(hbuf + (size_t)N_NODES * HID);// 16384
    float* sc     = shadow + 16384;                        // 256 (layout keep)
    unsigned short* W1T = (unsigned short*)(sc + 256);     // 16384 u16
    unsigned short* W2T = W1T + 16384;                     // 16384 u16
    int* head    = (int*)(W2T + 16384);                    // 100,000 * 16, node-major
    int2* pair   = (int2*)(head + NSUB * N_NODES);         // 1,600,000 int2 (8B aligned)

    // head = -1 (0xFF bytes); async memset is graph-capture safe
    hipMemsetAsync(head, 0xFF, (size_t)NSUB * N_NODES * sizeof(int), stream);

    // fused gate + build: 12500 gate blocks + 6250 build blocks, interleaved 2:1
    k_front<<<18750, 256, 0, stream>>>(x0, x1, mw, (unsigned*)out, shadow,
                                       W1, W2, W1T, W2T, ei, head, pair);
    k_agg<<<N_NODES / (4 * NPW), 256, 0, stream>>>((const unsigned*)out, pair, head,
                                                   (unsigned*)hbuf);
    k_mlp<<<MLP_BLOCKS, 256, 0, stream>>>(hbuf, W1T, W2T, b1, b2, shadow);
    k_bn2<<<BN_BLOCKS, 256, 0, stream>>>(hbuf, shadow, gamma, beta, out);
}